// Round 13
// baseline (563.165 us; speedup 1.0000x reference)
//
#include <hip/hip_runtime.h>
#include <math.h>

#define N_FFTC    1023
#define NFREQ     512
#define NBANDS    10
#define NPATH     32768
#define NSURF     16
#define NDIR      128
#define RIR_LEN   96000
#define FILT_LEN  1023
#define TWO_PI_D  6.283185307179586476925286766559
#define NBINS     93

typedef _Float16 f16x8 __attribute__((ext_vector_type(8)));
typedef float    f32x4 __attribute__((ext_vector_type(4)));

#define AS1 __attribute__((address_space(1)))
#define AS3 __attribute__((address_space(3)))
__device__ __forceinline__ void gload16(const void* g, void* l) {
    __builtin_amdgcn_global_load_lds((const AS1 void*)g, (AS3 void*)l, 16, 0, 0);
}

// ---- ws layout (bytes) ----
#define WS_RIR    0UL            // f32 [8][96000]               3,072,000
#define WS_WT     3072000UL      // f16 [1024][1024] hi          2,097,152
#define WS_TWC    5169152UL      // dbl [1023]
#define WS_TWS    5177600UL      // dbl [1023]
#define WS_LOGR   5185792UL      // f32 [16][10]
#define WS_SIGD   5186560UL      // f32 [128][10]
#define WS_GS     5191936UL      // dbl [10][512]
#define WS_GD     5232896UL      // dbl [10][512]
#define WS_TBL    5274112UL      // f32x4 [10][512]               81,920
#define WS_CNT    5356288UL      // int [8][93] (+pad)             4,096
#define WS_SLOT   5360384UL      // int [8][93] (+pad)             4,096
#define WS_PERM   5364480UL      // int [32768]                  131,072
#define WS_DLYS   5495552UL      // int [32768]                  131,072
#define WS_A      5626880UL      // f16 [chunkM][2048]  (4KB/path)

// ---------------- k0a: twiddles (fp64) + log_refl + sig_dir ----------------
__global__ void k0a_tables(const float* __restrict__ sp, const float* __restrict__ dp,
                           double* __restrict__ twc, double* __restrict__ tws,
                           float* __restrict__ logr, float* __restrict__ sigd)
{
    int idx = blockIdx.x * 256 + threadIdx.x;
    if (idx < 1023) {
        double ang = TWO_PI_D * (double)idx / 1023.0;
        twc[idx] = cos(ang);
        tws[idx] = sin(ang);
    } else if (idx >= 1024 && idx < 1024 + NSURF * NBANDS) {
        int i = idx - 1024;
        float s = 1.f / (1.f + expf(-sp[i]));
        logr[i] = logf(s <= 1e-9f ? 1e-9f : s);
    } else if (idx >= 2048 && idx < 2048 + NDIR * NBANDS) {
        int i = idx - 2048;
        sigd[i] = 1.f / (1.f + expf(-dp[i]));
    }
}

// ---------------- k0b: G[f][n] = sum_m c_m cos(2pi m n/N) * I[f][m] ----------------
__global__ void k0b_G(const float* __restrict__ SI, const float* __restrict__ DI,
                      const double* __restrict__ twc,
                      double* __restrict__ Gs, double* __restrict__ Gd)
{
    int idx = blockIdx.x * 256 + threadIdx.x;
    if (idx >= NBANDS * NFREQ) return;
    int f = idx >> 9, n = idx & 511;
    double gs = 0.0, gd = 0.0;
    for (int m = 0; m < NFREQ; ++m) {
        double c = (m == 0) ? 1.0 : 2.0;
        double t = c * twc[(m * n) % 1023];
        gs += t * (double)SI[f * NFREQ + m];
        gd += t * (double)DI[f * NFREQ + m];
    }
    Gs[idx] = gs;
    Gd[idx] = gd;
}

// ---------------- k0c: packed table {SI, DI, PST, PDT}[f][k] ----------------
__global__ void k0c_TBL(const double* __restrict__ tws,
                        const double* __restrict__ Gs, const double* __restrict__ Gd,
                        const float* __restrict__ SI, const float* __restrict__ DI,
                        float4* __restrict__ TBL)
{
    int idx = blockIdx.x * 256 + threadIdx.x;
    if (idx >= NBANDS * NFREQ) return;
    int f = idx >> 9, k = idx & 511;
    double ps = 0.0, pd_ = 0.0;
    for (int n = 1; n < 512; ++n) {
        double s = tws[(k * n) % 1023];
        ps  += s * Gs[f * NFREQ + n];
        pd_ += s * Gd[f * NFREQ + n];
    }
    double sc = -2.0 / 1023.0;
    float4 v;
    v.x = SI[idx];
    v.y = DI[idx];
    v.z = (float)(sc * ps);
    v.w = (float)(sc * pd_);
    TBL[idx] = v;
}

// ---------------- k0d: WT[t][k] synthesis matrix (transposed), f16 hi limb, x2^14 ----------------
__global__ void k0d_W(const double* __restrict__ twc, const double* __restrict__ tws,
                      _Float16* __restrict__ WThi)
{
    int idx = blockIdx.x * 256 + threadIdx.x;   // 1024*1024 over [t][k]
    int t = idx >> 10, k = idx & 1023;
    double v = 0.0;
    if (t < 1023) {
        if (k < 512) v = (((k == 0) ? 1.0 : 2.0) / 1023.0) * twc[(k * t) % 1023];
        else         v = (2.0 / 1023.0) * tws[((k - 512) * t) % 1023];
    }
    WThi[idx] = (_Float16)((float)(v * 16384.0));
}

// ---------------- kS: bin-group paths by delay (count -> scan -> scatter) ----------------
__global__ void kS1_count(const int* __restrict__ delays, int* __restrict__ cnt)
{
    int p = blockIdx.x * 256 + threadIdx.x;
    if (p < NPATH) atomicAdd(&cnt[(p >> 12) * NBINS + (delays[p] >> 10)], 1);
}

__global__ void kS2_scan(const int* __restrict__ cnt, int* __restrict__ slot)
{
    int b = threadIdx.x;
    if (b < 8) {
        int acc = 0;
        for (int i = 0; i < NBINS; ++i) { slot[b * NBINS + i] = acc; acc += cnt[b * NBINS + i]; }
    }
}

__global__ void kS3_scatter(const int* __restrict__ delays, int* __restrict__ slot,
                            int* __restrict__ perm, int* __restrict__ dlys)
{
    int p = blockIdx.x * 256 + threadIdx.x;
    if (p >= NPATH) return;
    int b = p >> 12, d = delays[p];
    int o = atomicAdd(&slot[b * NBINS + (d >> 10)], 1);
    int s = b * 4096 + o;
    perm[s] = p;
    dlys[s] = d;
}

__device__ __forceinline__ float wave_sum64(float v) {
#pragma unroll
    for (int m = 1; m < 64; m <<= 1) v += __shfl_xor(v, m, 64);
    return v;
}
__device__ __forceinline__ float wave_max64(float v) {
#pragma unroll
    for (int m = 1; m < 64; m <<= 1) v = fmaxf(v, __shfl_xor(v, m, 64));
    return v;
}

// ---------------- k1: 4 paths per wave (sorted order via perm); TBL amortized x4 ----------------
__global__ __launch_bounds__(256) void k1_ab(
    const float* __restrict__ path_dirs, const float* __restrict__ fib,
    const int* __restrict__ mask,
    const int* __restrict__ perm, const int* __restrict__ dlys,
    const float* __restrict__ logr, const float* __restrict__ sigd,
    const float4* __restrict__ TBL,
    _Float16* __restrict__ A, int chunkStart, int m)
{
    int wave = threadIdx.x >> 6, lane = threadIdx.x & 63;
    int pb = blockIdx.x * 16 + wave * 4;     // chunk-local sorted row base

    int n0 = lane, n1 = lane + 64;
    float fx0 = fib[n0 * 3], fy0 = fib[n0 * 3 + 1], fz0 = fib[n0 * 3 + 2];
    float fx1 = fib[n1 * 3], fy1 = fib[n1 * 3 + 1], fz1 = fib[n1 * 3 + 2];
    float sd0[10], sd1[10];
#pragma unroll
    for (int f = 0; f < NBANDS; ++f) {
        sd0[f] = sigd[n0 * NBANDS + f];
        sd1[f] = sigd[n1 * NBANDS + f];
    }

    int pgq[4];
#pragma unroll
    for (int pp = 0; pp < 4; ++pp) pgq[pp] = perm[chunkStart + pb + pp];

    float las[4][10], lad[4][10], gsc[4];
#pragma unroll
    for (int pp = 0; pp < 4; ++pp) {
        int pg = pgq[pp];
        float dx = path_dirs[pg * 3 + 0], dy = path_dirs[pg * 3 + 1], dz = path_dirs[pg * 3 + 2];
        float inv = 1.f / (sqrtf(dx * dx + dy * dy + dz * dz) + 1e-9f);
        dx *= inv; dy *= inv; dz *= inv;
        float l0 = 8.f * (dx * fx0 + dy * fy0 + dz * fz0);
        float l1 = 8.f * (dx * fx1 + dy * fy1 + dz * fz1);
        float mx = wave_max64(fmaxf(l0, l1));
        float e0 = __expf(l0 - mx), e1 = __expf(l1 - mx);
        float ssum = wave_sum64(e0 + e1);
        float w0 = e0 / ssum, w1 = e1 / ssum;
#pragma unroll
        for (int f = 0; f < NBANDS; ++f) {
            float part = wave_sum64(w0 * sd0[f] + w1 * sd1[f]);
            lad[pp][f] = __logf(part <= 1e-9f ? 1e-9f : part);
            las[pp][f] = 0.f;
        }
        int dly = dlys[chunkStart + pb + pp];
        float g = 1.f / fmaxf((float)dly / 48.f, 1.f);
        gsc[pp] = g * 16384.f;
    }

#pragma unroll
    for (int s = 0; s < NSURF; ++s) {
        float lr[10];
#pragma unroll
        for (int f = 0; f < NBANDS; ++f) lr[f] = logr[s * NBANDS + f];
#pragma unroll
        for (int pp = 0; pp < 4; ++pp) {
            float mv = (float)mask[(size_t)pgq[pp] * NSURF + s];
#pragma unroll
            for (int f = 0; f < NBANDS; ++f) las[pp][f] += mv * lr[f];
        }
    }

    for (int i = 0; i < 8; ++i) {
        int q = i * 64 + lane;
        float4 t[10];
#pragma unroll
        for (int f = 0; f < NBANDS; ++f) t[f] = TBL[f * NFREQ + q];
#pragma unroll
        for (int pp = 0; pp < 4; ++pp) {
            float la = 0.f, ph = 0.f;
#pragma unroll
            for (int f = 0; f < NBANDS; ++f) {
                la += las[pp][f] * t[f].x + lad[pp][f] * t[f].y;
                ph += las[pp][f] * t[f].z + lad[pp][f] * t[f].w;
            }
            float M = gsc[pp] * __expf(la);
            float sn, cs;
            __sincosf(ph, &sn, &cs);
            float av = M * cs, bv = M * sn;
            _Float16 ah = (_Float16)av, bh = (_Float16)bv;
            _Float16* row = A + (size_t)(pb + pp) * 2048;
            row[q]        = ah;
            row[512 + q]  = bh;
            row[1024 + q] = (_Float16)(av - (float)ah);
            row[1536 + q] = (_Float16)(bv - (float)bh);
        }
    }
}

// ---------------- k2: 256x256 dbuf f16 MFMA GEMM + fused windowed scatter ----------------
// C = (Ahi + Alo) * Whi over 32 K-tiles of 64 (K=2048). Paths are bin-grouped, so a
// 256-row tile spans ~6 delay bins: after the K-loop the 128KB LDS becomes the output
// window; LDS atomicAdd scatter + one global-atomic flush of nonzeros into rir.
#define NKT 32
__global__ __launch_bounds__(512) void k2_gemm(
    const _Float16* __restrict__ A, const _Float16* __restrict__ WT,
    const int* __restrict__ dlys, float* __restrict__ rir, int chunkStart)
{
    extern __shared__ __align__(16) char smem[];   // 131072 bytes

    int nwg = gridDim.x, bid = blockIdx.x;
    int swzb = (nwg & 7) ? bid : ((bid & 7) * (nwg >> 3) + (bid >> 3));
    int rowTile = swzb >> 2, colTile = swzb & 3;
    int p0 = rowTile * 256, t0 = colTile * 256;

    int tid = threadIdx.x, lane = tid & 63, wid = tid >> 6;
    int wr = wid >> 2, wc = wid & 3;
    int li = lane & 15, lg = lane >> 4, xr = li & 7;

    int srow = tid >> 3;
    int slot = (tid & 7) ^ (srow & 7);
    char* dstbase = smem + (tid & ~63) * 16;

    f32x4 acc[8][4];
#pragma unroll
    for (int i = 0; i < 8; ++i)
#pragma unroll
        for (int j = 0; j < 4; ++j) acc[i][j] = (f32x4){0.f, 0.f, 0.f, 0.f};

    auto stage = [&](int c, int hs, int kt) {
        int panel = kt >> 4;                       // 0 = Ahi, 1 = Alo
        int kk = (kt & 15) << 6;
        char* dst = dstbase + c * 65536 + ((hs >= 2) ? 32768 : 0) + (hs & 1) * 16384;
        if (hs < 2) {
            int aoff = ((panel == 1) ? 1024 : 0) + kk + slot * 8;
            const _Float16* g0 = A + (size_t)(p0 + (hs & 1) * 128 + srow) * 2048 + aoff;
            gload16(g0, dst);
            gload16(g0 + (size_t)64 * 2048, dst + 8192);
        } else {
            int koff = kk + slot * 8;
            const _Float16* g0 = WT + (size_t)(t0 + (hs & 1) * 128 + srow) * 1024 + koff;
            gload16(g0, dst);
            gload16(g0 + (size_t)64 * 1024, dst + 8192);
        }
    };

#pragma unroll
    for (int hs = 0; hs < 4; ++hs) stage(0, hs, 0);

    int browLocal0 = (wc & 1) * 64;

    for (int kt = 0; kt < NKT; ++kt) {
        int c = kt & 1;
        int ktn = (kt + 1 < NKT) ? (kt + 1) : 0;
        const char* bufA = smem + c * 65536 + wr * 16384;
        const char* bufB = smem + c * 65536 + 32768 + (wc >> 1) * 16384;

        f16x8 bf[4][2];
#pragma unroll
        for (int ph = 0; ph < 4; ++ph) {
            stage(c ^ 1, ph, ktn);
            if (ph == 0) asm volatile("s_waitcnt vmcnt(2)" ::: "memory");
            __builtin_amdgcn_s_barrier();

            f16x8 af[2][2];
#pragma unroll
            for (int m2 = 0; m2 < 2; ++m2) {
                int row = (ph * 2 + m2) * 16 + li;
#pragma unroll
                for (int ks = 0; ks < 2; ++ks)
                    af[m2][ks] = *(const f16x8*)(bufA + row * 128 + (((ks * 4 + lg) ^ xr) << 4));
            }
            if (ph == 0) {
#pragma unroll
                for (int n = 0; n < 4; ++n) {
                    int row = browLocal0 + n * 16 + li;
#pragma unroll
                    for (int ks = 0; ks < 2; ++ks)
                        bf[n][ks] = *(const f16x8*)(bufB + row * 128 + (((ks * 4 + lg) ^ xr) << 4));
                }
            }
            __builtin_amdgcn_s_setprio(1);
#pragma unroll
            for (int m2 = 0; m2 < 2; ++m2)
#pragma unroll
                for (int n = 0; n < 4; ++n)
#pragma unroll
                    for (int ks = 0; ks < 2; ++ks)
                        acc[ph * 2 + m2][n] = __builtin_amdgcn_mfma_f32_16x16x32_f16(
                            af[m2][ks], bf[n][ks], acc[ph * 2 + m2][n], 0, 0, 0);
            __builtin_amdgcn_s_setprio(0);
            __builtin_amdgcn_s_barrier();
        }
    }

    // -------- fused epilogue: LDS window scatter + flush to rir --------
    const float dsc = 1.f / (16384.f * 16384.f);
    __syncthreads();                         // K-loop LDS dead; full waitcnt drain
    float* win = (float*)smem;
    int sbase = chunkStart + p0;
    int b = sbase >> 12;                     // 4096 sorted rows per batch
    int firstbin = dlys[sbase] >> 10;
    int lastbin  = dlys[sbase + 255] >> 10;  // bin-grouped => nondecreasing
    int base = firstbin << 10;
    int wext = ((lastbin - firstbin) << 10) + 1024 + 256;
    float* rb = rir + (size_t)b * RIR_LEN;

    if (wext <= 32768) {
        for (int i = tid; i < wext; i += 512) win[i] = 0.f;
        __syncthreads();
#pragma unroll
        for (int m = 0; m < 8; ++m) {
            int rl = wr * 128 + m * 16 + lg * 4;
#pragma unroll
            for (int r = 0; r < 4; ++r) {
                int d = dlys[sbase + rl + r];
                int wi = d - base + wc * 64 + li;
#pragma unroll
                for (int n = 0; n < 4; ++n)
                    atomicAdd(&win[wi + n * 16], acc[m][n][r] * dsc);
            }
        }
        __syncthreads();
        for (int i = tid; i < wext; i += 512) {
            float v = win[i];
            int t = base + t0 + i;
            if (v != 0.f && t < RIR_LEN) atomicAdd(&rb[t], v);
        }
    } else {                                 // statistical never-path fallback
#pragma unroll
        for (int m = 0; m < 8; ++m) {
            int rl = wr * 128 + m * 16 + lg * 4;
#pragma unroll
            for (int r = 0; r < 4; ++r) {
                int d = dlys[sbase + rl + r];
#pragma unroll
                for (int n = 0; n < 4; ++n)
                    atomicAdd(&rb[d + t0 + wc * 64 + n * 16 + li], acc[m][n][r] * dsc);
            }
        }
    }
}

// ---------------- k3: 'same' cross-correlation; 8 out/thread, skewed LDS (R5-proven) ----------------
#define SEG 2048
#define SK(i) ((i) + ((i) >> 5))
__global__ __launch_bounds__(256) void k3_conv(
    const float* __restrict__ rir, const float* __restrict__ kern, float* __restrict__ out)
{
    __shared__ float rs[3184];
    __shared__ float ks[FILT_LEN];
    int b = blockIdx.y;
    int t0 = blockIdx.x * SEG;
    for (int i = threadIdx.x; i < FILT_LEN; i += 256) ks[i] = kern[i];
    for (int i = threadIdx.x; i < SEG + FILT_LEN - 1 + 8; i += 256) {
        int t = t0 - 511 + i;
        rs[SK(i)] = (t >= 0 && t < RIR_LEN) ? rir[(size_t)b * RIR_LEN + t] : 0.f;
    }
    __syncthreads();

    int base = threadIdx.x * 8;
    float a0 = 0.f, a1 = 0.f, a2 = 0.f, a3 = 0.f, a4 = 0.f, a5 = 0.f, a6 = 0.f, a7 = 0.f;
    float w0 = rs[SK(base + 0)], w1 = rs[SK(base + 1)], w2 = rs[SK(base + 2)], w3 = rs[SK(base + 3)];
    float w4 = rs[SK(base + 4)], w5 = rs[SK(base + 5)], w6 = rs[SK(base + 6)], w7 = rs[SK(base + 7)];
#pragma unroll 8
    for (int k = 0; k < FILT_LEN; ++k) {
        float kv = ks[k];
        a0 = fmaf(kv, w0, a0); a1 = fmaf(kv, w1, a1);
        a2 = fmaf(kv, w2, a2); a3 = fmaf(kv, w3, a3);
        a4 = fmaf(kv, w4, a4); a5 = fmaf(kv, w5, a5);
        a6 = fmaf(kv, w6, a6); a7 = fmaf(kv, w7, a7);
        w0 = w1; w1 = w2; w2 = w3; w3 = w4; w4 = w5; w5 = w6; w6 = w7;
        w7 = rs[SK(base + k + 8)];
    }
    int t = t0 + base;
    size_t ob = (size_t)b * RIR_LEN;
    if (t + 7 < RIR_LEN) {
        float4 v0 = {a0, a1, a2, a3}, v1 = {a4, a5, a6, a7};
        *(float4*)&out[ob + t]     = v0;
        *(float4*)&out[ob + t + 4] = v1;
    } else {
        float av[8] = {a0, a1, a2, a3, a4, a5, a6, a7};
        for (int j = 0; j < 8; ++j)
            if (t + j < RIR_LEN) out[ob + t + j] = av[j];
    }
}

extern "C" void kernel_launch(void* const* d_in, const int* in_sizes, int n_in,
                              void* d_out, int out_size, void* d_ws, size_t ws_size,
                              hipStream_t stream)
{
    const float* surface_params = (const float*)d_in[0];
    const float* dir_params     = (const float*)d_in[1];
    const float* path_dirs      = (const float*)d_in[2];
    const float* source_kernel  = (const float*)d_in[3];
    const float* surf_interp    = (const float*)d_in[4];
    const float* dir_interp     = (const float*)d_in[5];
    const float* fib_points     = (const float*)d_in[6];
    const int*   mask           = (const int*)d_in[7];
    const int*   delays         = (const int*)d_in[8];
    float* out = (float*)d_out;
    char*  ws  = (char*)d_ws;

    float*     rir  = (float*)(ws + WS_RIR);
    _Float16*  WT   = (_Float16*)(ws + WS_WT);
    double*    twc  = (double*)(ws + WS_TWC);
    double*    tws  = (double*)(ws + WS_TWS);
    float*     logr = (float*)(ws + WS_LOGR);
    float*     sigd = (float*)(ws + WS_SIGD);
    double*    Gs   = (double*)(ws + WS_GS);
    double*    Gd   = (double*)(ws + WS_GD);
    float4*    TBL  = (float4*)(ws + WS_TBL);
    int*       cnt  = (int*)(ws + WS_CNT);
    int*       slt  = (int*)(ws + WS_SLOT);
    int*       perm = (int*)(ws + WS_PERM);
    int*       dlys = (int*)(ws + WS_DLYS);
    _Float16*  A    = (_Float16*)(ws + WS_A);

    hipFuncSetAttribute((const void*)k2_gemm,
                        hipFuncAttributeMaxDynamicSharedMemorySize, 131072);

    // adaptive chunking: 4KB per path (A only), multiple of 256
    size_t abCap = (ws_size > WS_A) ? (ws_size - WS_A) : 0;
    long long cm = (long long)((abCap / 4096) & ~(size_t)255);
    if (cm > NPATH) cm = NPATH;
    if (cm < 256)   cm = 256;
    int chunkM = (int)cm;

    hipMemsetAsync(rir, 0, (size_t)8 * RIR_LEN * sizeof(float), stream);
    hipMemsetAsync(cnt, 0, 4096, stream);

    k0a_tables <<<16, 256, 0, stream>>>(surface_params, dir_params, twc, tws, logr, sigd);
    k0b_G      <<<20, 256, 0, stream>>>(surf_interp, dir_interp, twc, Gs, Gd);
    k0c_TBL    <<<20, 256, 0, stream>>>(tws, Gs, Gd, surf_interp, dir_interp, TBL);
    k0d_W      <<<4096, 256, 0, stream>>>(twc, tws, WT);
    kS1_count  <<<NPATH / 256, 256, 0, stream>>>(delays, cnt);
    kS2_scan   <<<1, 64, 0, stream>>>(cnt, slt);
    kS3_scatter<<<NPATH / 256, 256, 0, stream>>>(delays, slt, perm, dlys);

    for (int cs = 0; cs < NPATH; cs += chunkM) {
        int m = NPATH - cs;
        if (m > chunkM) m = chunkM;
        k1_ab<<<m / 16, 256, 0, stream>>>(path_dirs, fib_points, mask, perm, dlys,
                                          logr, sigd, TBL, A, cs, m);
        k2_gemm<<<(m / 256) * 4, 512, 131072, stream>>>(A, WT, dlys, rir, cs);
    }

    dim3 g3((RIR_LEN + SEG - 1) / SEG, 8);
    k3_conv<<<g3, 256, 0, stream>>>(rir, source_kernel, out);
}

// Round 15
// 524.475 us; speedup vs baseline: 1.0738x; 1.0738x over previous
//
#include <hip/hip_runtime.h>
#include <math.h>

#define N_FFTC    1023
#define NFREQ     512
#define NBANDS    10
#define NPATH     32768
#define NSURF     16
#define NDIR      128
#define RIR_LEN   96000
#define FILT_LEN  1023
#define TWO_PI_D  6.283185307179586476925286766559
#define NBINS     93

typedef _Float16 f16x8 __attribute__((ext_vector_type(8)));
typedef float    f32x4 __attribute__((ext_vector_type(4)));

#define AS1 __attribute__((address_space(1)))
#define AS3 __attribute__((address_space(3)))
__device__ __forceinline__ void gload16(const void* g, void* l) {
    __builtin_amdgcn_global_load_lds((const AS1 void*)g, (AS3 void*)l, 16, 0, 0);
}

// ---- ws layout (bytes) ----
#define WS_WT     0UL            // f16 [1024][1024] hi          2,097,152
#define WS_TWC    2097152UL      // dbl [1023]
#define WS_TWS    2105600UL      // dbl [1023]
#define WS_LOGR   2113792UL      // f32 [16][10]
#define WS_SIGD   2114816UL      // f32 [128][10]
#define WS_GS     2120192UL      // dbl [10][512]
#define WS_GD     2161152UL      // dbl [10][512]
#define WS_TBL    2202112UL      // f32x4 [10][512]               81,920
#define WS_CNT    2284032UL      // int [8][93] (+pad)             4,096
#define WS_SLOT   2288128UL      // int [8][93] (+pad)             4,096
#define WS_SBASE  2292224UL      // int [8][94] (+pad)             4,096
#define WS_PERM   2296320UL      // int [32768]                  131,072
#define WS_DLYS   2427392UL      // int [32768]                  131,072
#define WS_WB     2558464UL      // f32 [8][93][2048]            6,094,848
#define WS_A      8653312UL      // f16 [chunkM][2048] (4KB/path) then f32 filt [chunkM][1024]

// ---------------- k0a: twiddles (fp64) + log_refl + sig_dir ----------------
__global__ void k0a_tables(const float* __restrict__ sp, const float* __restrict__ dp,
                           double* __restrict__ twc, double* __restrict__ tws,
                           float* __restrict__ logr, float* __restrict__ sigd)
{
    int idx = blockIdx.x * 256 + threadIdx.x;
    if (idx < 1023) {
        double ang = TWO_PI_D * (double)idx / 1023.0;
        twc[idx] = cos(ang);
        tws[idx] = sin(ang);
    } else if (idx >= 1024 && idx < 1024 + NSURF * NBANDS) {
        int i = idx - 1024;
        float s = 1.f / (1.f + expf(-sp[i]));
        logr[i] = logf(s <= 1e-9f ? 1e-9f : s);
    } else if (idx >= 2048 && idx < 2048 + NDIR * NBANDS) {
        int i = idx - 2048;
        sigd[i] = 1.f / (1.f + expf(-dp[i]));
    }
}

// ---------------- k0b: G[f][n] = sum_m c_m cos(2pi m n/N) * I[f][m] ----------------
__global__ void k0b_G(const float* __restrict__ SI, const float* __restrict__ DI,
                      const double* __restrict__ twc,
                      double* __restrict__ Gs, double* __restrict__ Gd)
{
    int idx = blockIdx.x * 256 + threadIdx.x;
    if (idx >= NBANDS * NFREQ) return;
    int f = idx >> 9, n = idx & 511;
    double gs = 0.0, gd = 0.0;
    for (int m = 0; m < NFREQ; ++m) {
        double c = (m == 0) ? 1.0 : 2.0;
        double t = c * twc[(m * n) % 1023];
        gs += t * (double)SI[f * NFREQ + m];
        gd += t * (double)DI[f * NFREQ + m];
    }
    Gs[idx] = gs;
    Gd[idx] = gd;
}

// ---------------- k0c: packed table {SI, DI, PST, PDT}[f][k] ----------------
__global__ void k0c_TBL(const double* __restrict__ tws,
                        const double* __restrict__ Gs, const double* __restrict__ Gd,
                        const float* __restrict__ SI, const float* __restrict__ DI,
                        float4* __restrict__ TBL)
{
    int idx = blockIdx.x * 256 + threadIdx.x;
    if (idx >= NBANDS * NFREQ) return;
    int f = idx >> 9, k = idx & 511;
    double ps = 0.0, pd_ = 0.0;
    for (int n = 1; n < 512; ++n) {
        double s = tws[(k * n) % 1023];
        ps  += s * Gs[f * NFREQ + n];
        pd_ += s * Gd[f * NFREQ + n];
    }
    double sc = -2.0 / 1023.0;
    float4 v;
    v.x = SI[idx];
    v.y = DI[idx];
    v.z = (float)(sc * ps);
    v.w = (float)(sc * pd_);
    TBL[idx] = v;
}

// ---------------- k0d: WT[t][k] synthesis matrix (transposed), f16 hi limb, x2^14 ----------------
__global__ void k0d_W(const double* __restrict__ twc, const double* __restrict__ tws,
                      _Float16* __restrict__ WThi)
{
    int idx = blockIdx.x * 256 + threadIdx.x;   // 1024*1024 over [t][k]
    int t = idx >> 10, k = idx & 1023;
    double v = 0.0;
    if (t < 1023) {
        if (k < 512) v = (((k == 0) ? 1.0 : 2.0) / 1023.0) * twc[(k * t) % 1023];
        else         v = (2.0 / 1023.0) * tws[((k - 512) * t) % 1023];
    }
    WThi[idx] = (_Float16)((float)(v * 16384.0));
}

// ---------------- kS: bin-group paths by delay (count -> scan -> scatter) ----------------
__global__ void kS1_count(const int* __restrict__ delays, int* __restrict__ cnt)
{
    int p = blockIdx.x * 256 + threadIdx.x;
    if (p < NPATH) atomicAdd(&cnt[(p >> 12) * NBINS + (delays[p] >> 10)], 1);
}

__global__ void kS2_scan(const int* __restrict__ cnt, int* __restrict__ slot,
                         int* __restrict__ sbase)
{
    int b = threadIdx.x;
    if (b < 8) {
        int acc = 0;
        for (int i = 0; i < NBINS; ++i) {
            slot[b * NBINS + i]  = acc;
            sbase[b * 94 + i]    = acc;
            acc += cnt[b * NBINS + i];
        }
        sbase[b * 94 + NBINS] = acc;   // = 4096
    }
}

__global__ void kS3_scatter(const int* __restrict__ delays, int* __restrict__ slot,
                            int* __restrict__ perm, int* __restrict__ dlys)
{
    int p = blockIdx.x * 256 + threadIdx.x;
    if (p >= NPATH) return;
    int b = p >> 12, d = delays[p];
    int o = atomicAdd(&slot[b * NBINS + (d >> 10)], 1);
    int s = b * 4096 + o;
    perm[s] = p;
    dlys[s] = d;
}

__device__ __forceinline__ float wave_sum64(float v) {
#pragma unroll
    for (int m = 1; m < 64; m <<= 1) v += __shfl_xor(v, m, 64);
    return v;
}
__device__ __forceinline__ float wave_max64(float v) {
#pragma unroll
    for (int m = 1; m < 64; m <<= 1) v = fmaxf(v, __shfl_xor(v, m, 64));
    return v;
}

// ---------------- k1: 4 paths per wave (sorted order via perm); TBL amortized x4 ----------------
__global__ __launch_bounds__(256) void k1_ab(
    const float* __restrict__ path_dirs, const float* __restrict__ fib,
    const int* __restrict__ mask,
    const int* __restrict__ perm, const int* __restrict__ dlys,
    const float* __restrict__ logr, const float* __restrict__ sigd,
    const float4* __restrict__ TBL,
    _Float16* __restrict__ A, int chunkStart, int m)
{
    int wave = threadIdx.x >> 6, lane = threadIdx.x & 63;
    int pb = blockIdx.x * 16 + wave * 4;     // chunk-local sorted row base

    int n0 = lane, n1 = lane + 64;
    float fx0 = fib[n0 * 3], fy0 = fib[n0 * 3 + 1], fz0 = fib[n0 * 3 + 2];
    float fx1 = fib[n1 * 3], fy1 = fib[n1 * 3 + 1], fz1 = fib[n1 * 3 + 2];
    float sd0[10], sd1[10];
#pragma unroll
    for (int f = 0; f < NBANDS; ++f) {
        sd0[f] = sigd[n0 * NBANDS + f];
        sd1[f] = sigd[n1 * NBANDS + f];
    }

    int pgq[4];
#pragma unroll
    for (int pp = 0; pp < 4; ++pp) pgq[pp] = perm[chunkStart + pb + pp];

    float las[4][10], lad[4][10], gsc[4];
#pragma unroll
    for (int pp = 0; pp < 4; ++pp) {
        int pg = pgq[pp];
        float dx = path_dirs[pg * 3 + 0], dy = path_dirs[pg * 3 + 1], dz = path_dirs[pg * 3 + 2];
        float inv = 1.f / (sqrtf(dx * dx + dy * dy + dz * dz) + 1e-9f);
        dx *= inv; dy *= inv; dz *= inv;
        float l0 = 8.f * (dx * fx0 + dy * fy0 + dz * fz0);
        float l1 = 8.f * (dx * fx1 + dy * fy1 + dz * fz1);
        float mx = wave_max64(fmaxf(l0, l1));
        float e0 = __expf(l0 - mx), e1 = __expf(l1 - mx);
        float ssum = wave_sum64(e0 + e1);
        float w0 = e0 / ssum, w1 = e1 / ssum;
#pragma unroll
        for (int f = 0; f < NBANDS; ++f) {
            float part = wave_sum64(w0 * sd0[f] + w1 * sd1[f]);
            lad[pp][f] = __logf(part <= 1e-9f ? 1e-9f : part);
            las[pp][f] = 0.f;
        }
        int dly = dlys[chunkStart + pb + pp];
        float g = 1.f / fmaxf((float)dly / 48.f, 1.f);
        gsc[pp] = g * 16384.f;
    }

#pragma unroll
    for (int s = 0; s < NSURF; ++s) {
        float lr[10];
#pragma unroll
        for (int f = 0; f < NBANDS; ++f) lr[f] = logr[s * NBANDS + f];
#pragma unroll
        for (int pp = 0; pp < 4; ++pp) {
            float mv = (float)mask[(size_t)pgq[pp] * NSURF + s];
#pragma unroll
            for (int f = 0; f < NBANDS; ++f) las[pp][f] += mv * lr[f];
        }
    }

    for (int i = 0; i < 8; ++i) {
        int q = i * 64 + lane;
        float4 t[10];
#pragma unroll
        for (int f = 0; f < NBANDS; ++f) t[f] = TBL[f * NFREQ + q];
#pragma unroll
        for (int pp = 0; pp < 4; ++pp) {
            float la = 0.f, ph = 0.f;
#pragma unroll
            for (int f = 0; f < NBANDS; ++f) {
                la += las[pp][f] * t[f].x + lad[pp][f] * t[f].y;
                ph += las[pp][f] * t[f].z + lad[pp][f] * t[f].w;
            }
            float M = gsc[pp] * __expf(la);
            float sn, cs;
            __sincosf(ph, &sn, &cs);
            float av = M * cs, bv = M * sn;
            _Float16 ah = (_Float16)av, bh = (_Float16)bv;
            _Float16* row = A + (size_t)(pb + pp) * 2048;
            row[q]        = ah;
            row[512 + q]  = bh;
            row[1024 + q] = (_Float16)(av - (float)ah);
            row[1536 + q] = (_Float16)(bv - (float)bh);
        }
    }
}

// ---------------- k2: 256x256 dbuf f16 MFMA GEMM, counted vmcnt (R11-proven, pure) ----------------
// C = (Ahi + Alo) * Whi over 32 K-tiles of 64 (K=2048); rows in bin-sorted order.
#define NKT 32
__global__ __launch_bounds__(512) void k2_gemm(
    const _Float16* __restrict__ A, const _Float16* __restrict__ WT,
    float* __restrict__ filt)
{
    extern __shared__ __align__(16) char smem[];   // 131072 bytes

    int nwg = gridDim.x, bid = blockIdx.x;
    int swzb = (nwg & 7) ? bid : ((bid & 7) * (nwg >> 3) + (bid >> 3));
    int rowTile = swzb >> 2, colTile = swzb & 3;
    int p0 = rowTile * 256, t0 = colTile * 256;

    int tid = threadIdx.x, lane = tid & 63, wid = tid >> 6;
    int wr = wid >> 2, wc = wid & 3;
    int li = lane & 15, lg = lane >> 4, xr = li & 7;

    int srow = tid >> 3;
    int slot = (tid & 7) ^ (srow & 7);
    char* dstbase = smem + (tid & ~63) * 16;

    f32x4 acc[8][4];
#pragma unroll
    for (int i = 0; i < 8; ++i)
#pragma unroll
        for (int j = 0; j < 4; ++j) acc[i][j] = (f32x4){0.f, 0.f, 0.f, 0.f};

    auto stage = [&](int c, int hs, int kt) {
        int panel = kt >> 4;                       // 0 = Ahi, 1 = Alo
        int kk = (kt & 15) << 6;
        char* dst = dstbase + c * 65536 + ((hs >= 2) ? 32768 : 0) + (hs & 1) * 16384;
        if (hs < 2) {
            int aoff = ((panel == 1) ? 1024 : 0) + kk + slot * 8;
            const _Float16* g0 = A + (size_t)(p0 + (hs & 1) * 128 + srow) * 2048 + aoff;
            gload16(g0, dst);
            gload16(g0 + (size_t)64 * 2048, dst + 8192);
        } else {
            int koff = kk + slot * 8;
            const _Float16* g0 = WT + (size_t)(t0 + (hs & 1) * 128 + srow) * 1024 + koff;
            gload16(g0, dst);
            gload16(g0 + (size_t)64 * 1024, dst + 8192);
        }
    };

#pragma unroll
    for (int hs = 0; hs < 4; ++hs) stage(0, hs, 0);

    int browLocal0 = (wc & 1) * 64;

    for (int kt = 0; kt < NKT; ++kt) {
        int c = kt & 1;
        int ktn = (kt + 1 < NKT) ? (kt + 1) : 0;
        const char* bufA = smem + c * 65536 + wr * 16384;
        const char* bufB = smem + c * 65536 + 32768 + (wc >> 1) * 16384;

        f16x8 bf[4][2];
#pragma unroll
        for (int ph = 0; ph < 4; ++ph) {
            stage(c ^ 1, ph, ktn);
            if (ph == 0) asm volatile("s_waitcnt vmcnt(2)" ::: "memory");
            __builtin_amdgcn_s_barrier();

            f16x8 af[2][2];
#pragma unroll
            for (int m2 = 0; m2 < 2; ++m2) {
                int row = (ph * 2 + m2) * 16 + li;
#pragma unroll
                for (int ks = 0; ks < 2; ++ks)
                    af[m2][ks] = *(const f16x8*)(bufA + row * 128 + (((ks * 4 + lg) ^ xr) << 4));
            }
            if (ph == 0) {
#pragma unroll
                for (int n = 0; n < 4; ++n) {
                    int row = browLocal0 + n * 16 + li;
#pragma unroll
                    for (int ks = 0; ks < 2; ++ks)
                        bf[n][ks] = *(const f16x8*)(bufB + row * 128 + (((ks * 4 + lg) ^ xr) << 4));
                }
            }
            __builtin_amdgcn_s_setprio(1);
#pragma unroll
            for (int m2 = 0; m2 < 2; ++m2)
#pragma unroll
                for (int n = 0; n < 4; ++n)
#pragma unroll
                    for (int ks = 0; ks < 2; ++ks)
                        acc[ph * 2 + m2][n] = __builtin_amdgcn_mfma_f32_16x16x32_f16(
                            af[m2][ks], bf[n][ks], acc[ph * 2 + m2][n], 0, 0, 0);
            __builtin_amdgcn_s_setprio(0);
            __builtin_amdgcn_s_barrier();
        }
    }

    const float dsc = 1.f / (16384.f * 16384.f);
#pragma unroll
    for (int m = 0; m < 8; ++m) {
        int prow = p0 + wr * 128 + m * 16 + lg * 4;
#pragma unroll
        for (int r = 0; r < 4; ++r) {
            float* fp = filt + (size_t)(prow + r) * 1024 + t0 + wc * 64 + li;
#pragma unroll
            for (int n = 0; n < 4; ++n)
                fp[n * 16] = acc[m][n][r] * dsc;
        }
    }
}

// ---------------- k4: CONTIGUOUS gather (bin-sorted filt) -> WB; skewed per-wave windows ----------------
#define SKW(j) ((j) + ((j) >> 5))
__global__ __launch_bounds__(256) void k4_scatter(
    const float* __restrict__ filt, const int* __restrict__ dlys,
    const int* __restrict__ sbase, float* __restrict__ WB, int chunkStart, int m)
{
    __shared__ float win4[4][2112];
    int b = blockIdx.y, bin = blockIdx.x;
    int binStart = bin << 10;
    int wid = threadIdx.x >> 6, lane = threadIdx.x & 63;

    for (int i = lane; i < 2112; i += 64) win4[wid][i] = 0.f;   // own window -> no barrier

    int lo = b * 4096 + sbase[b * 94 + bin];
    int hi = b * 4096 + sbase[b * 94 + bin + 1];
    if (lo < chunkStart) lo = chunkStart;
    if (hi > chunkStart + m) hi = chunkStart + m;

    float* w = win4[wid];
    for (int j = lo + wid; j < hi; j += 4) {            // contiguous slab, 4-wave split
        int off = dlys[j] - binStart;                   // wave-uniform
        const float4* fr = (const float4*)(filt + (size_t)(j - chunkStart) * 1024);
        float4 v0 = fr[lane], v1 = fr[64 + lane], v2 = fr[128 + lane], v3 = fr[192 + lane];
        int jj = off + lane * 4;
        w[SKW(jj + 0)] += v0.x; w[SKW(jj + 1)] += v0.y; w[SKW(jj + 2)] += v0.z; w[SKW(jj + 3)] += v0.w;
        jj += 256;
        w[SKW(jj + 0)] += v1.x; w[SKW(jj + 1)] += v1.y; w[SKW(jj + 2)] += v1.z; w[SKW(jj + 3)] += v1.w;
        jj += 256;
        w[SKW(jj + 0)] += v2.x; w[SKW(jj + 1)] += v2.y; w[SKW(jj + 2)] += v2.z; w[SKW(jj + 3)] += v2.w;
        jj += 256;
        w[SKW(jj + 0)] += v3.x; w[SKW(jj + 1)] += v3.y; w[SKW(jj + 2)] += v3.z; w[SKW(jj + 3)] += v3.w;
    }
    __syncthreads();

    float* wb = WB + ((size_t)b * NBINS + bin) * 2048;
    if (chunkStart == 0) {
        for (int i = threadIdx.x; i < 2048; i += 256)
            wb[i] = win4[0][SKW(i)] + win4[1][SKW(i)] + win4[2][SKW(i)] + win4[3][SKW(i)];
    } else {
        for (int i = threadIdx.x; i < 2048; i += 256)
            wb[i] += win4[0][SKW(i)] + win4[1][SKW(i)] + win4[2][SKW(i)] + win4[3][SKW(i)];
    }
}

// ---------------- k3: 'same' cross-correlation reading WB pairs (R11-proven) ----------------
#define SEG 2048
#define SK(i) ((i) + ((i) >> 5))
__global__ __launch_bounds__(256) void k3_conv(
    const float* __restrict__ WB, const float* __restrict__ kern, float* __restrict__ out)
{
    __shared__ float rs[3184];
    __shared__ float ks[FILT_LEN];
    int b = blockIdx.y;
    int t0 = blockIdx.x * SEG;
    const float* wbb = WB + (size_t)b * NBINS * 2048;
    for (int i = threadIdx.x; i < FILT_LEN; i += 256) ks[i] = kern[i];
    for (int i = threadIdx.x; i < SEG + FILT_LEN - 1 + 8; i += 256) {
        int t = t0 - 511 + i;
        float v = 0.f;
        if (t >= 0 && t < RIR_LEN) {
            int bn = t >> 10, o = t & 1023;
            if (bn < NBINS) v = wbb[bn * 2048 + o];
            if (bn >= 1)    v += wbb[(bn - 1) * 2048 + o + 1024];
        }
        rs[SK(i)] = v;
    }
    __syncthreads();

    int base = threadIdx.x * 8;
    float a0 = 0.f, a1 = 0.f, a2 = 0.f, a3 = 0.f, a4 = 0.f, a5 = 0.f, a6 = 0.f, a7 = 0.f;
    float w0 = rs[SK(base + 0)], w1 = rs[SK(base + 1)], w2 = rs[SK(base + 2)], w3 = rs[SK(base + 3)];
    float w4 = rs[SK(base + 4)], w5 = rs[SK(base + 5)], w6 = rs[SK(base + 6)], w7 = rs[SK(base + 7)];
#pragma unroll 8
    for (int k = 0; k < FILT_LEN; ++k) {
        float kv = ks[k];
        a0 = fmaf(kv, w0, a0); a1 = fmaf(kv, w1, a1);
        a2 = fmaf(kv, w2, a2); a3 = fmaf(kv, w3, a3);
        a4 = fmaf(kv, w4, a4); a5 = fmaf(kv, w5, a5);
        a6 = fmaf(kv, w6, a6); a7 = fmaf(kv, w7, a7);
        w0 = w1; w1 = w2; w2 = w3; w3 = w4; w4 = w5; w5 = w6; w6 = w7;
        w7 = rs[SK(base + k + 8)];
    }
    int t = t0 + base;
    size_t ob = (size_t)b * RIR_LEN;
    if (t + 7 < RIR_LEN) {
        float4 v0 = {a0, a1, a2, a3}, v1 = {a4, a5, a6, a7};
        *(float4*)&out[ob + t]     = v0;
        *(float4*)&out[ob + t + 4] = v1;
    } else {
        float av[8] = {a0, a1, a2, a3, a4, a5, a6, a7};
        for (int j = 0; j < 8; ++j)
            if (t + j < RIR_LEN) out[ob + t + j] = av[j];
    }
}

extern "C" void kernel_launch(void* const* d_in, const int* in_sizes, int n_in,
                              void* d_out, int out_size, void* d_ws, size_t ws_size,
                              hipStream_t stream)
{
    const float* surface_params = (const float*)d_in[0];
    const float* dir_params     = (const float*)d_in[1];
    const float* path_dirs      = (const float*)d_in[2];
    const float* source_kernel  = (const float*)d_in[3];
    const float* surf_interp    = (const float*)d_in[4];
    const float* dir_interp     = (const float*)d_in[5];
    const float* fib_points     = (const float*)d_in[6];
    const int*   mask           = (const int*)d_in[7];
    const int*   delays         = (const int*)d_in[8];
    float* out = (float*)d_out;
    char*  ws  = (char*)d_ws;

    _Float16*  WT    = (_Float16*)(ws + WS_WT);
    double*    twc   = (double*)(ws + WS_TWC);
    double*    tws   = (double*)(ws + WS_TWS);
    float*     logr  = (float*)(ws + WS_LOGR);
    float*     sigd  = (float*)(ws + WS_SIGD);
    double*    Gs    = (double*)(ws + WS_GS);
    double*    Gd    = (double*)(ws + WS_GD);
    float4*    TBL   = (float4*)(ws + WS_TBL);
    int*       cnt   = (int*)(ws + WS_CNT);
    int*       slt   = (int*)(ws + WS_SLOT);
    int*       sbase = (int*)(ws + WS_SBASE);
    int*       perm  = (int*)(ws + WS_PERM);
    int*       dlys  = (int*)(ws + WS_DLYS);
    float*     WB    = (float*)(ws + WS_WB);
    _Float16*  A     = (_Float16*)(ws + WS_A);

    (void)hipFuncSetAttribute((const void*)k2_gemm,
                              hipFuncAttributeMaxDynamicSharedMemorySize, 131072);

    // adaptive chunking: 8KB per path (A 4KB + filt 4KB), multiple of 256
    size_t abCap = (ws_size > WS_A) ? (ws_size - WS_A) : 0;
    long long cm = (long long)((abCap / 8192) & ~(size_t)255);
    if (cm > NPATH) cm = NPATH;
    if (cm < 256)   cm = 256;
    int chunkM = (int)cm;
    float* filt = (float*)(ws + WS_A + (size_t)chunkM * 4096);

    (void)hipMemsetAsync(cnt, 0, 4096, stream);

    k0a_tables <<<16, 256, 0, stream>>>(surface_params, dir_params, twc, tws, logr, sigd);
    k0b_G      <<<20, 256, 0, stream>>>(surf_interp, dir_interp, twc, Gs, Gd);
    k0c_TBL    <<<20, 256, 0, stream>>>(tws, Gs, Gd, surf_interp, dir_interp, TBL);
    k0d_W      <<<4096, 256, 0, stream>>>(twc, tws, WT);
    kS1_count  <<<NPATH / 256, 256, 0, stream>>>(delays, cnt);
    kS2_scan   <<<1, 64, 0, stream>>>(cnt, slt, sbase);
    kS3_scatter<<<NPATH / 256, 256, 0, stream>>>(delays, slt, perm, dlys);

    for (int cs = 0; cs < NPATH; cs += chunkM) {
        int m = NPATH - cs;
        if (m > chunkM) m = chunkM;
        k1_ab<<<m / 16, 256, 0, stream>>>(path_dirs, fib_points, mask, perm, dlys,
                                          logr, sigd, TBL, A, cs, m);
        k2_gemm<<<(m / 256) * 4, 512, 131072, stream>>>(A, WT, filt);
        dim3 g4(NBINS, 8);
        k4_scatter<<<g4, 256, 0, stream>>>(filt, dlys, sbase, WB, cs, m);
    }

    dim3 g3((RIR_LEN + SEG - 1) / SEG, 8);
    k3_conv<<<g3, 256, 0, stream>>>(WB, source_kernel, out);
}

// Round 16
// 363.593 us; speedup vs baseline: 1.5489x; 1.4425x over previous
//
#include <hip/hip_runtime.h>
#include <math.h>

#define N_FFTC    1023
#define NFREQ     512
#define NBANDS    10
#define NPATH     32768
#define NSURF     16
#define NDIR      128
#define RIR_LEN   96000
#define FILT_LEN  1023
#define TWO_PI_D  6.283185307179586476925286766559
#define BS        1024
#define NBINS     93

typedef _Float16 f16x8 __attribute__((ext_vector_type(8)));
typedef float    f32x4 __attribute__((ext_vector_type(4)));

#define AS1 __attribute__((address_space(1)))
#define AS3 __attribute__((address_space(3)))
__device__ __forceinline__ void gload16(const void* g, void* l) {
    __builtin_amdgcn_global_load_lds((const AS1 void*)g, (AS3 void*)l, 16, 0, 0);
}

// ---- ws layout (bytes) ----
#define WS_WT     0UL            // f16 [1024][1024] hi           2,097,152
#define WS_TWC    2097152UL      // dbl [1023]                        8,192
#define WS_TWS    2105344UL      // dbl [1023]                        8,192
#define WS_LOGR   2113536UL      // f32 [16][10]                      1,024
#define WS_SIGD   2114560UL      // f32 [128][10]                     5,120
#define WS_GS     2119680UL      // dbl [10][512]                    40,960
#define WS_GD     2160640UL      // dbl [10][512]                    40,960
#define WS_TBL    2201600UL      // f32x4 [10][512]                  81,920
#define WS_WB     2283520UL      // f32 [8][93][2048]             6,094,848
#define WS_A      8378368UL      // f16 [chunkM][1024] (2KB/path) then f32 filt [chunkM][1024]

// ---------------- k0a: twiddles (fp64) + log_refl + sig_dir ----------------
__global__ void k0a_tables(const float* __restrict__ sp, const float* __restrict__ dp,
                           double* __restrict__ twc, double* __restrict__ tws,
                           float* __restrict__ logr, float* __restrict__ sigd)
{
    int idx = blockIdx.x * 256 + threadIdx.x;
    if (idx < 1023) {
        double ang = TWO_PI_D * (double)idx / 1023.0;
        twc[idx] = cos(ang);
        tws[idx] = sin(ang);
    } else if (idx >= 1024 && idx < 1024 + NSURF * NBANDS) {
        int i = idx - 1024;
        float s = 1.f / (1.f + expf(-sp[i]));
        logr[i] = logf(s <= 1e-9f ? 1e-9f : s);
    } else if (idx >= 2048 && idx < 2048 + NDIR * NBANDS) {
        int i = idx - 2048;
        sigd[i] = 1.f / (1.f + expf(-dp[i]));
    }
}

// ---------------- k0b: G[f][n] = sum_m c_m cos(2pi m n/N) * I[f][m] ----------------
__global__ void k0b_G(const float* __restrict__ SI, const float* __restrict__ DI,
                      const double* __restrict__ twc,
                      double* __restrict__ Gs, double* __restrict__ Gd)
{
    int idx = blockIdx.x * 256 + threadIdx.x;
    if (idx >= NBANDS * NFREQ) return;
    int f = idx >> 9, n = idx & 511;
    double gs = 0.0, gd = 0.0;
    for (int m = 0; m < NFREQ; ++m) {
        double c = (m == 0) ? 1.0 : 2.0;
        double t = c * twc[(m * n) % 1023];
        gs += t * (double)SI[f * NFREQ + m];
        gd += t * (double)DI[f * NFREQ + m];
    }
    Gs[idx] = gs;
    Gd[idx] = gd;
}

// ---------------- k0c: packed table {SI, DI, PST, PDT}[f][k] ----------------
__global__ void k0c_TBL(const double* __restrict__ tws,
                        const double* __restrict__ Gs, const double* __restrict__ Gd,
                        const float* __restrict__ SI, const float* __restrict__ DI,
                        float4* __restrict__ TBL)
{
    int idx = blockIdx.x * 256 + threadIdx.x;
    if (idx >= NBANDS * NFREQ) return;
    int f = idx >> 9, k = idx & 511;
    double ps = 0.0, pd_ = 0.0;
    for (int n = 1; n < 512; ++n) {
        double s = tws[(k * n) % 1023];
        ps  += s * Gs[f * NFREQ + n];
        pd_ += s * Gd[f * NFREQ + n];
    }
    double sc = -2.0 / 1023.0;
    float4 v;
    v.x = SI[idx];
    v.y = DI[idx];
    v.z = (float)(sc * ps);
    v.w = (float)(sc * pd_);
    TBL[idx] = v;
}

// ---------------- k0d: WT[t][k] synthesis matrix (transposed), f16 hi limb, x2^14 ----------------
__global__ void k0d_W(const double* __restrict__ twc, const double* __restrict__ tws,
                      _Float16* __restrict__ WThi)
{
    int idx = blockIdx.x * 256 + threadIdx.x;   // 1024*1024 over [t][k]
    int t = idx >> 10, k = idx & 1023;
    double v = 0.0;
    if (t < 1023) {
        if (k < 512) v = (((k == 0) ? 1.0 : 2.0) / 1023.0) * twc[(k * t) % 1023];
        else         v = (2.0 / 1023.0) * tws[((k - 512) * t) % 1023];
    }
    WThi[idx] = (_Float16)((float)(v * 16384.0));
}

__device__ __forceinline__ float wave_sum64(float v) {
#pragma unroll
    for (int m = 1; m < 64; m <<= 1) v += __shfl_xor(v, m, 64);
    return v;
}
__device__ __forceinline__ float wave_max64(float v) {
#pragma unroll
    for (int m = 1; m < 64; m <<= 1) v = fmaxf(v, __shfl_xor(v, m, 64));
    return v;
}

// ---------------- k1: 4 paths per wave; TBL amortized x4; f16 a,b only (no lo limbs) ----------------
__global__ __launch_bounds__(256) void k1_ab(
    const float* __restrict__ path_dirs, const float* __restrict__ fib,
    const int* __restrict__ mask, const int* __restrict__ delays,
    const float* __restrict__ logr, const float* __restrict__ sigd,
    const float4* __restrict__ TBL,
    _Float16* __restrict__ A, int chunkStart, int m)
{
    int wave = threadIdx.x >> 6, lane = threadIdx.x & 63;
    int pb = blockIdx.x * 16 + wave * 4;

    int n0 = lane, n1 = lane + 64;
    float fx0 = fib[n0 * 3], fy0 = fib[n0 * 3 + 1], fz0 = fib[n0 * 3 + 2];
    float fx1 = fib[n1 * 3], fy1 = fib[n1 * 3 + 1], fz1 = fib[n1 * 3 + 2];
    float sd0[10], sd1[10];
#pragma unroll
    for (int f = 0; f < NBANDS; ++f) {
        sd0[f] = sigd[n0 * NBANDS + f];
        sd1[f] = sigd[n1 * NBANDS + f];
    }

    float las[4][10], lad[4][10], gsc[4];
#pragma unroll
    for (int pp = 0; pp < 4; ++pp) {
        int pg = chunkStart + pb + pp;
        float dx = path_dirs[pg * 3 + 0], dy = path_dirs[pg * 3 + 1], dz = path_dirs[pg * 3 + 2];
        float inv = 1.f / (sqrtf(dx * dx + dy * dy + dz * dz) + 1e-9f);
        dx *= inv; dy *= inv; dz *= inv;
        float l0 = 8.f * (dx * fx0 + dy * fy0 + dz * fz0);
        float l1 = 8.f * (dx * fx1 + dy * fy1 + dz * fz1);
        float mx = wave_max64(fmaxf(l0, l1));
        float e0 = __expf(l0 - mx), e1 = __expf(l1 - mx);
        float ssum = wave_sum64(e0 + e1);
        float w0 = e0 / ssum, w1 = e1 / ssum;
#pragma unroll
        for (int f = 0; f < NBANDS; ++f) {
            float part = wave_sum64(w0 * sd0[f] + w1 * sd1[f]);
            lad[pp][f] = __logf(part <= 1e-9f ? 1e-9f : part);
            las[pp][f] = 0.f;
        }
        int dly = delays[pg];
        float g = 1.f / fmaxf((float)dly / 48.f, 1.f);
        gsc[pp] = g * 16384.f;   // fold 2^14 MFMA-denorm-guard scale
    }

#pragma unroll
    for (int s = 0; s < NSURF; ++s) {
        float lr[10];
#pragma unroll
        for (int f = 0; f < NBANDS; ++f) lr[f] = logr[s * NBANDS + f];
#pragma unroll
        for (int pp = 0; pp < 4; ++pp) {
            float mv = (float)mask[(size_t)(chunkStart + pb + pp) * NSURF + s];
#pragma unroll
            for (int f = 0; f < NBANDS; ++f) las[pp][f] += mv * lr[f];
        }
    }

    for (int i = 0; i < 8; ++i) {
        int q = i * 64 + lane;
        float4 t[10];
#pragma unroll
        for (int f = 0; f < NBANDS; ++f) t[f] = TBL[f * NFREQ + q];
#pragma unroll
        for (int pp = 0; pp < 4; ++pp) {
            float la = 0.f, ph = 0.f;
#pragma unroll
            for (int f = 0; f < NBANDS; ++f) {
                la += las[pp][f] * t[f].x + lad[pp][f] * t[f].y;
                ph += las[pp][f] * t[f].z + lad[pp][f] * t[f].w;
            }
            float M = gsc[pp] * __expf(la);
            float sn, cs;
            __sincosf(ph, &sn, &cs);
            _Float16* row = A + (size_t)(pb + pp) * 1024;
            row[q]       = (_Float16)(M * cs);
            row[512 + q] = (_Float16)(M * sn);
        }
    }
}

// ---------------- k2: 256x256 dbuf f16 MFMA GEMM, counted vmcnt; K=1024 (Ahi*Whi) ----------------
// Wlo and Alo limbs dropped: each contributes ~2^-12 relative (measured Wlo: +4.8e-7 absmax).
#define NKT 16
__global__ __launch_bounds__(512) void k2_gemm(
    const _Float16* __restrict__ A, const _Float16* __restrict__ WT,
    float* __restrict__ filt)
{
    extern __shared__ __align__(16) char smem[];   // 131072 bytes

    int nwg = gridDim.x, bid = blockIdx.x;
    int swzb = (nwg & 7) ? bid : ((bid & 7) * (nwg >> 3) + (bid >> 3));
    int rowTile = swzb >> 2, colTile = swzb & 3;
    int p0 = rowTile * 256, t0 = colTile * 256;

    int tid = threadIdx.x, lane = tid & 63, wid = tid >> 6;
    int wr = wid >> 2, wc = wid & 3;
    int li = lane & 15, lg = lane >> 4, xr = li & 7;

    int srow = tid >> 3;
    int slot = (tid & 7) ^ (srow & 7);
    char* dstbase = smem + (tid & ~63) * 16;

    f32x4 acc[8][4];
#pragma unroll
    for (int i = 0; i < 8; ++i)
#pragma unroll
        for (int j = 0; j < 4; ++j) acc[i][j] = (f32x4){0.f, 0.f, 0.f, 0.f};

    auto stage = [&](int c, int hs, int kt) {
        int kk = (kt & 15) << 6;
        int off = kk + slot * 8;
        char* dst = dstbase + c * 65536 + ((hs >= 2) ? 32768 : 0) + (hs & 1) * 16384;
        if (hs < 2) {
            const _Float16* g0 = A + (size_t)(p0 + (hs & 1) * 128 + srow) * 1024 + off;
            gload16(g0, dst);
            gload16(g0 + (size_t)64 * 1024, dst + 8192);
        } else {
            const _Float16* g0 = WT + (size_t)(t0 + (hs & 1) * 128 + srow) * 1024 + off;
            gload16(g0, dst);
            gload16(g0 + (size_t)64 * 1024, dst + 8192);
        }
    };

#pragma unroll
    for (int hs = 0; hs < 4; ++hs) stage(0, hs, 0);

    int browLocal0 = (wc & 1) * 64;

    for (int kt = 0; kt < NKT; ++kt) {
        int c = kt & 1;
        int ktn = (kt + 1 < NKT) ? (kt + 1) : 0;
        const char* bufA = smem + c * 65536 + wr * 16384;
        const char* bufB = smem + c * 65536 + 32768 + (wc >> 1) * 16384;

        f16x8 bf[4][2];
#pragma unroll
        for (int ph = 0; ph < 4; ++ph) {
            stage(c ^ 1, ph, ktn);
            if (ph == 0) asm volatile("s_waitcnt vmcnt(2)" ::: "memory");
            __builtin_amdgcn_s_barrier();

            f16x8 af[2][2];
#pragma unroll
            for (int m2 = 0; m2 < 2; ++m2) {
                int row = (ph * 2 + m2) * 16 + li;
#pragma unroll
                for (int ks = 0; ks < 2; ++ks)
                    af[m2][ks] = *(const f16x8*)(bufA + row * 128 + (((ks * 4 + lg) ^ xr) << 4));
            }
            if (ph == 0) {
#pragma unroll
                for (int n = 0; n < 4; ++n) {
                    int row = browLocal0 + n * 16 + li;
#pragma unroll
                    for (int ks = 0; ks < 2; ++ks)
                        bf[n][ks] = *(const f16x8*)(bufB + row * 128 + (((ks * 4 + lg) ^ xr) << 4));
                }
            }
            __builtin_amdgcn_s_setprio(1);
#pragma unroll
            for (int m2 = 0; m2 < 2; ++m2)
#pragma unroll
                for (int n = 0; n < 4; ++n)
#pragma unroll
                    for (int ks = 0; ks < 2; ++ks)
                        acc[ph * 2 + m2][n] = __builtin_amdgcn_mfma_f32_16x16x32_f16(
                            af[m2][ks], bf[n][ks], acc[ph * 2 + m2][n], 0, 0, 0);
            __builtin_amdgcn_s_setprio(0);
            __builtin_amdgcn_s_barrier();
        }
    }

    const float dsc = 1.f / (16384.f * 16384.f);  // exact 2^-28
#pragma unroll
    for (int m = 0; m < 8; ++m) {
        int prow = p0 + wr * 128 + m * 16 + lg * 4;
#pragma unroll
        for (int r = 0; r < 4; ++r) {
            float* fp = filt + (size_t)(prow + r) * 1024 + t0 + wc * 64 + li;
#pragma unroll
            for (int n = 0; n < 4; ++n)
                fp[n * 16] = acc[m][n][r] * dsc;
        }
    }
}

// ---------------- k4: binned scatter filt -> WB; skewed per-wave windows (R10/R11-proven) ----------------
#define SKW(j) ((j) + ((j) >> 5))
__global__ __launch_bounds__(256) void k4_scatter(
    const float* __restrict__ filt, const int* __restrict__ delays,
    float* __restrict__ WB, int chunkStart, int m)
{
    __shared__ float win4[4][2112];
    int b = blockIdx.y, bin = blockIdx.x;
    int binStart = bin << 10;
    int wid = threadIdx.x >> 6, lane = threadIdx.x & 63;

    for (int i = lane; i < 2112; i += 64) win4[wid][i] = 0.f;

    float* w = win4[wid];
    auto ACC = [&](int off, float4 v0, float4 v1, float4 v2, float4 v3) {
        int j = off + lane * 4;
        w[SKW(j + 0)] += v0.x; w[SKW(j + 1)] += v0.y; w[SKW(j + 2)] += v0.z; w[SKW(j + 3)] += v0.w;
        j += 256;
        w[SKW(j + 0)] += v1.x; w[SKW(j + 1)] += v1.y; w[SKW(j + 2)] += v1.z; w[SKW(j + 3)] += v1.w;
        j += 256;
        w[SKW(j + 0)] += v2.x; w[SKW(j + 1)] += v2.y; w[SKW(j + 2)] += v2.z; w[SKW(j + 3)] += v2.w;
        j += 256;
        w[SKW(j + 0)] += v3.x; w[SKW(j + 1)] += v3.y; w[SKW(j + 2)] += v3.z; w[SKW(j + 3)] += v3.w;
    };

    int lo = b * 4096, hi = lo + 4096;
    if (lo < chunkStart) lo = chunkStart;
    if (hi > chunkStart + m) hi = chunkStart + m;

    for (int base = lo + wid * 64; base < hi; base += 256) {
        int p = base + lane;
        int d = (p < hi) ? delays[p] : -1;
        bool match = (d >= binStart) && (d < binStart + BS);
        unsigned long long mask = __ballot(match);
        while (mask) {
            int bit0 = __ffsll(mask) - 1; mask &= mask - 1;
            bool has2 = (mask != 0);
            int bit1 = bit0;
            if (has2) { bit1 = __ffsll(mask) - 1; mask &= mask - 1; }
            int off0 = __shfl(d, bit0) - binStart;
            int off1 = __shfl(d, bit1) - binStart;
            const float4* fr0 = (const float4*)(filt + (size_t)(base + bit0 - chunkStart) * 1024);
            const float4* fr1 = (const float4*)(filt + (size_t)(base + bit1 - chunkStart) * 1024);
            float4 a0 = fr0[lane], a1 = fr0[64 + lane], a2 = fr0[128 + lane], a3 = fr0[192 + lane];
            if (has2) {
                float4 b0 = fr1[lane], b1 = fr1[64 + lane], b2 = fr1[128 + lane], b3 = fr1[192 + lane];
                ACC(off0, a0, a1, a2, a3);
                ACC(off1, b0, b1, b2, b3);
            } else {
                ACC(off0, a0, a1, a2, a3);
            }
        }
    }
    __syncthreads();

    float* wb = WB + ((size_t)b * NBINS + bin) * 2048;
    if (chunkStart == 0) {
        for (int i = threadIdx.x; i < 2048; i += 256)
            wb[i] = win4[0][SKW(i)] + win4[1][SKW(i)] + win4[2][SKW(i)] + win4[3][SKW(i)];
    } else {
        for (int i = threadIdx.x; i < 2048; i += 256)
            wb[i] += win4[0][SKW(i)] + win4[1][SKW(i)] + win4[2][SKW(i)] + win4[3][SKW(i)];
    }
}

// ---------------- k3: 'same' cross-correlation reading WB pairs (R11-proven) ----------------
#define SEG 2048
#define SK(i) ((i) + ((i) >> 5))
__global__ __launch_bounds__(256) void k3_conv(
    const float* __restrict__ WB, const float* __restrict__ kern, float* __restrict__ out)
{
    __shared__ float rs[3184];
    __shared__ float ks[FILT_LEN];
    int b = blockIdx.y;
    int t0 = blockIdx.x * SEG;
    const float* wbb = WB + (size_t)b * NBINS * 2048;
    for (int i = threadIdx.x; i < FILT_LEN; i += 256) ks[i] = kern[i];
    for (int i = threadIdx.x; i < SEG + FILT_LEN - 1 + 8; i += 256) {
        int t = t0 - 511 + i;
        float v = 0.f;
        if (t >= 0 && t < RIR_LEN) {
            int bn = t >> 10, o = t & 1023;
            if (bn < NBINS) v = wbb[bn * 2048 + o];
            if (bn >= 1)    v += wbb[(bn - 1) * 2048 + o + 1024];
        }
        rs[SK(i)] = v;
    }
    __syncthreads();

    int base = threadIdx.x * 8;
    float a0 = 0.f, a1 = 0.f, a2 = 0.f, a3 = 0.f, a4 = 0.f, a5 = 0.f, a6 = 0.f, a7 = 0.f;
    float w0 = rs[SK(base + 0)], w1 = rs[SK(base + 1)], w2 = rs[SK(base + 2)], w3 = rs[SK(base + 3)];
    float w4 = rs[SK(base + 4)], w5 = rs[SK(base + 5)], w6 = rs[SK(base + 6)], w7 = rs[SK(base + 7)];
#pragma unroll 8
    for (int k = 0; k < FILT_LEN; ++k) {
        float kv = ks[k];
        a0 = fmaf(kv, w0, a0); a1 = fmaf(kv, w1, a1);
        a2 = fmaf(kv, w2, a2); a3 = fmaf(kv, w3, a3);
        a4 = fmaf(kv, w4, a4); a5 = fmaf(kv, w5, a5);
        a6 = fmaf(kv, w6, a6); a7 = fmaf(kv, w7, a7);
        w0 = w1; w1 = w2; w2 = w3; w3 = w4; w4 = w5; w5 = w6; w6 = w7;
        w7 = rs[SK(base + k + 8)];
    }
    int t = t0 + base;
    size_t ob = (size_t)b * RIR_LEN;
    if (t + 7 < RIR_LEN) {
        float4 v0 = {a0, a1, a2, a3}, v1 = {a4, a5, a6, a7};
        *(float4*)&out[ob + t]     = v0;
        *(float4*)&out[ob + t + 4] = v1;
    } else {
        float av[8] = {a0, a1, a2, a3, a4, a5, a6, a7};
        for (int j = 0; j < 8; ++j)
            if (t + j < RIR_LEN) out[ob + t + j] = av[j];
    }
}

extern "C" void kernel_launch(void* const* d_in, const int* in_sizes, int n_in,
                              void* d_out, int out_size, void* d_ws, size_t ws_size,
                              hipStream_t stream)
{
    const float* surface_params = (const float*)d_in[0];
    const float* dir_params     = (const float*)d_in[1];
    const float* path_dirs      = (const float*)d_in[2];
    const float* source_kernel  = (const float*)d_in[3];
    const float* surf_interp    = (const float*)d_in[4];
    const float* dir_interp     = (const float*)d_in[5];
    const float* fib_points     = (const float*)d_in[6];
    const int*   mask           = (const int*)d_in[7];
    const int*   delays         = (const int*)d_in[8];
    float* out = (float*)d_out;
    char*  ws  = (char*)d_ws;

    _Float16*  WT   = (_Float16*)(ws + WS_WT);
    double*    twc  = (double*)(ws + WS_TWC);
    double*    tws  = (double*)(ws + WS_TWS);
    float*     logr = (float*)(ws + WS_LOGR);
    float*     sigd = (float*)(ws + WS_SIGD);
    double*    Gs   = (double*)(ws + WS_GS);
    double*    Gd   = (double*)(ws + WS_GD);
    float4*    TBL  = (float4*)(ws + WS_TBL);
    float*     WB   = (float*)(ws + WS_WB);
    _Float16*  A    = (_Float16*)(ws + WS_A);

    (void)hipFuncSetAttribute((const void*)k2_gemm,
                              hipFuncAttributeMaxDynamicSharedMemorySize, 131072);

    // adaptive chunking: 6KB per path (A 2KB + filt 4KB), multiple of 256
    size_t abCap = (ws_size > WS_A) ? (ws_size - WS_A) : 0;
    long long cm = (long long)((abCap / 6144) & ~(size_t)255);
    if (cm > NPATH) cm = NPATH;
    if (cm < 256)   cm = 256;
    int chunkM = (int)cm;
    float* filt = (float*)(ws + WS_A + (size_t)chunkM * 2048);

    k0a_tables<<<16, 256, 0, stream>>>(surface_params, dir_params, twc, tws, logr, sigd);
    k0b_G     <<<20, 256, 0, stream>>>(surf_interp, dir_interp, twc, Gs, Gd);
    k0c_TBL   <<<20, 256, 0, stream>>>(tws, Gs, Gd, surf_interp, dir_interp, TBL);
    k0d_W     <<<4096, 256, 0, stream>>>(twc, tws, WT);

    for (int cs = 0; cs < NPATH; cs += chunkM) {
        int m = NPATH - cs;
        if (m > chunkM) m = chunkM;
        k1_ab<<<m / 16, 256, 0, stream>>>(path_dirs, fib_points, mask, delays,
                                          logr, sigd, TBL, A, cs, m);
        k2_gemm<<<(m / 256) * 4, 512, 131072, stream>>>(A, WT, filt);
        dim3 g4(NBINS, 8);
        k4_scatter<<<g4, 256, 0, stream>>>(filt, delays, WB, cs, m);
    }

    dim3 g3((RIR_LEN + SEG - 1) / SEG, 8);
    k3_conv<<<g3, 256, 0, stream>>>(WB, source_kernel, out);
}